// Round 2
// baseline (6405.415 us; speedup 1.0000x reference)
//
#include <hip/hip_runtime.h>

typedef unsigned long long u64_t;

#define S_LEN 2048
#define EDIM  1024
#define HDIM  1024
#define GDIM  4096   // 4*H

// ---------------------------------------------------------------------------
// Phase A: ix[t][r] = emb[tokens[t]] . W_ih[r] + b_ih[r] + b_hh[r]
// fp32 LDS-tiled GEMM, 64x64 tile, BK=16, 256 threads, 4x4 micro-tile.
// ---------------------------------------------------------------------------
__global__ __launch_bounds__(256)
void ix_gemm(const int* __restrict__ tokens, const float* __restrict__ emb,
             const float* __restrict__ Wih, const float* __restrict__ bih,
             const float* __restrict__ bhh, float* __restrict__ ix)
{
    __shared__ float As[16][68];
    __shared__ float Bs[16][68];
    const int t0  = blockIdx.x * 64;
    const int r0  = blockIdx.y * 64;
    const int tid = threadIdx.x;
    const int tx  = tid & 15;          // n-direction
    const int ty  = tid >> 4;          // m-direction
    const int m_a = tid & 63;          // staging row
    const int k_a = (tid >> 6) << 2;   // staging k offset: 0,4,8,12

    const float* arow = emb + (size_t)tokens[t0 + m_a] * EDIM + k_a;
    const float* brow = Wih + (size_t)(r0 + m_a) * EDIM + k_a;

    float acc[4][4] = {};
    for (int kk = 0; kk < EDIM; kk += 16) {
        float4 av = *(const float4*)(arow + kk);
        float4 bv = *(const float4*)(brow + kk);
        __syncthreads();
        As[k_a + 0][m_a] = av.x; As[k_a + 1][m_a] = av.y;
        As[k_a + 2][m_a] = av.z; As[k_a + 3][m_a] = av.w;
        Bs[k_a + 0][m_a] = bv.x; Bs[k_a + 1][m_a] = bv.y;
        Bs[k_a + 2][m_a] = bv.z; Bs[k_a + 3][m_a] = bv.w;
        __syncthreads();
#pragma unroll
        for (int k = 0; k < 16; ++k) {
            float4 a = *(const float4*)&As[k][ty << 2];
            float4 b = *(const float4*)&Bs[k][tx << 2];
            acc[0][0] += a.x * b.x; acc[0][1] += a.x * b.y;
            acc[0][2] += a.x * b.z; acc[0][3] += a.x * b.w;
            acc[1][0] += a.y * b.x; acc[1][1] += a.y * b.y;
            acc[1][2] += a.y * b.z; acc[1][3] += a.y * b.w;
            acc[2][0] += a.z * b.x; acc[2][1] += a.z * b.y;
            acc[2][2] += a.z * b.z; acc[2][3] += a.z * b.w;
            acc[3][0] += a.w * b.x; acc[3][1] += a.w * b.y;
            acc[3][2] += a.w * b.z; acc[3][3] += a.w * b.w;
        }
    }
    const int n0 = r0 + (tx << 2);
    float b0 = bih[n0 + 0] + bhh[n0 + 0];
    float b1 = bih[n0 + 1] + bhh[n0 + 1];
    float b2 = bih[n0 + 2] + bhh[n0 + 2];
    float b3 = bih[n0 + 3] + bhh[n0 + 3];
#pragma unroll
    for (int i = 0; i < 4; ++i) {
        int m = t0 + (ty << 2) + i;
        float4 v = make_float4(acc[i][0] + b0, acc[i][1] + b1,
                               acc[i][2] + b2, acc[i][3] + b3);
        *(float4*)(ix + (size_t)m * GDIM + n0) = v;
    }
}

// ---------------------------------------------------------------------------
// Phase B: persistent recurrence. 256 blocks x 256 threads = 1024 waves.
// Wave j owns gate rows {j, H+j, 2H+j, 3H+j} of W_hh, held in registers
// (16 fp32 / lane / gate). h hand-off: u64 {step_tag<<32 | f32bits} in a
// 2-deep rotating buffer, agent-scope relaxed atomics (tag and data share
// one word, so no ordering fence is needed).
// ---------------------------------------------------------------------------
__device__ __forceinline__ float fast_sigmoid(float x) {
    return 1.0f / (1.0f + __expf(-x));
}
__device__ __forceinline__ float fast_tanh(float x) {
    return 1.0f - 2.0f / (__expf(2.0f * x) + 1.0f);
}

__global__ __launch_bounds__(256)
void lstm_rec(const float* __restrict__ Whh,   // [4H, H]
              const float* __restrict__ ix,    // [S, 4H]
              u64_t* hbuf,                     // [2][H] tagged
              float* __restrict__ out)         // [H]
{
    const int tid  = threadIdx.x;
    const int wid  = tid >> 6;
    const int lane = tid & 63;
    const int j    = blockIdx.x * 4 + wid;     // 0..1023

    __shared__ float hs[HDIM];

    // Load this wave's weights into registers (coalesced: k = lane + 64*m).
    float wi[16], wf[16], wg[16], wo[16];
    const float* Wi = Whh + (size_t)j * HDIM;
    const float* Wf = Whh + (size_t)(HDIM  + j) * HDIM;
    const float* Wg = Whh + (size_t)(2*HDIM + j) * HDIM;
    const float* Wo = Whh + (size_t)(3*HDIM + j) * HDIM;
#pragma unroll
    for (int m = 0; m < 16; ++m) {
        int k = lane + (m << 6);
        wi[m] = Wi[k]; wf[m] = Wf[k]; wg[m] = Wg[k]; wo[m] = Wo[k];
    }

    float c = 0.0f;

    for (int t = 0; t < S_LEN; ++t) {
        // Input-gate contributions (wave-uniform broadcast loads); issued
        // before the poll so their latency overlaps the wait.
        const float* ixt = ix + (size_t)t * GDIM;
        float bi = ixt[j];
        float bf = ixt[HDIM + j];
        float bg = ixt[2 * HDIM + j];
        float bo = ixt[3 * HDIM + j];

        if (t == 0) {
            hs[tid]       = 0.0f;
            hs[256 + tid] = 0.0f;
            hs[512 + tid] = 0.0f;
            hs[768 + tid] = 0.0f;
        } else {
            u64_t* src = hbuf + (size_t)((t - 1) & 1) * HDIM;
            const u64_t want = (u64_t)(t - 1);
            u64_t v0, v1, v2, v3;
            for (;;) {
                v0 = __hip_atomic_load(src + tid,       __ATOMIC_RELAXED, __HIP_MEMORY_SCOPE_AGENT);
                v1 = __hip_atomic_load(src + 256 + tid, __ATOMIC_RELAXED, __HIP_MEMORY_SCOPE_AGENT);
                v2 = __hip_atomic_load(src + 512 + tid, __ATOMIC_RELAXED, __HIP_MEMORY_SCOPE_AGENT);
                v3 = __hip_atomic_load(src + 768 + tid, __ATOMIC_RELAXED, __HIP_MEMORY_SCOPE_AGENT);
                if ((v0 >> 32) == want && (v1 >> 32) == want &&
                    (v2 >> 32) == want && (v3 >> 32) == want) break;
                __builtin_amdgcn_s_sleep(1);
            }
            hs[tid]       = __uint_as_float((unsigned)v0);
            hs[256 + tid] = __uint_as_float((unsigned)v1);
            hs[512 + tid] = __uint_as_float((unsigned)v2);
            hs[768 + tid] = __uint_as_float((unsigned)v3);
        }
        __syncthreads();

        // Partial dot products ONLY (bias added once, after the reduce —
        // adding it per-lane before the butterfly multiplies it by 64).
        float si = 0.0f, sf = 0.0f, sg = 0.0f, so = 0.0f;
#pragma unroll
        for (int m = 0; m < 16; ++m) {
            float h = hs[lane + (m << 6)];
            si += wi[m] * h;
            sf += wf[m] * h;
            sg += wg[m] * h;
            so += wo[m] * h;
        }
        // Butterfly all-reduce across the 64-lane wave (4 independent chains).
#pragma unroll
        for (int s = 32; s > 0; s >>= 1) {
            si += __shfl_xor(si, s, 64);
            sf += __shfl_xor(sf, s, 64);
            sg += __shfl_xor(sg, s, 64);
            so += __shfl_xor(so, s, 64);
        }
        si += bi; sf += bf; sg += bg; so += bo;

        float ig = fast_sigmoid(si);
        float fg = fast_sigmoid(sf);
        float og = fast_sigmoid(so);
        float gt = fast_tanh(sg);
        c = fg * c + ig * gt;
        float h = og * fast_tanh(c);

        if (lane == 0) {
            u64_t val = ((u64_t)(unsigned)t << 32) | (u64_t)__float_as_uint(h);
            __hip_atomic_store(hbuf + (size_t)(t & 1) * HDIM + j, val,
                               __ATOMIC_RELAXED, __HIP_MEMORY_SCOPE_AGENT);
            if (t == S_LEN - 1) out[j] = h;
        }
        __syncthreads();  // protect hs until all waves consumed it
    }
}

// ---------------------------------------------------------------------------
extern "C" void kernel_launch(void* const* d_in, const int* in_sizes, int n_in,
                              void* d_out, int out_size, void* d_ws, size_t ws_size,
                              hipStream_t stream) {
    const int*   tokens = (const int*)  d_in[0];
    const float* emb    = (const float*)d_in[1];
    const float* Wih    = (const float*)d_in[2];
    const float* Whh    = (const float*)d_in[3];
    const float* bih    = (const float*)d_in[4];
    const float* bhh    = (const float*)d_in[5];
    float* out = (float*)d_out;

    float* ix   = (float*)d_ws;                                     // 33.55 MB
    u64_t* hbuf = (u64_t*)((char*)d_ws + (size_t)S_LEN * GDIM * 4); // 16 KB

    dim3 gA(S_LEN / 64, GDIM / 64);
    hipLaunchKernelGGL(ix_gemm, gA, dim3(256), 0, stream,
                       tokens, emb, Wih, bih, bhh, ix);
    hipLaunchKernelGGL(lstm_rec, dim3(256), dim3(256), 0, stream,
                       Whh, ix, hbuf, out);
}